// Round 11
// baseline (8436.408 us; speedup 1.0000x reference)
//
#include <hip/hip_runtime.h>
#include <cstdint>

#define SQ 4096
#define FD 256
#define HD 512
#define GD 2048

// workspace layout (float elements)
#define WS_X       0                         // x [4096][512]
#define WS_XPROJ   (WS_X + SQ*HD)            // xproj [2][4096][2048]
#define WS_WT      (WS_XPROJ + 2*SQ*GD)      // conv_w transposed [2][256][256]
#define WS_LINT    (WS_WT + 2*FD*FD)         // lin_w transposed [256][256]
#define WS_SYNC    (WS_LINT + FD*FD)         // payload u64[2][2][256][8] = 64 KB

typedef __attribute__((ext_vector_type(4))) float f32x4;
typedef unsigned long long u64;

__device__ __forceinline__ float sigf(float x) { return 1.f / (1.f + __expf(-x)); }
// tanh(x) = 2*sigmoid(2x) - 1  (one __expf; |err| ~1e-7)
__device__ __forceinline__ float tanh_s(float x) { return fmaf(2.f, sigf(2.f * x), -1.f); }

#define REP16(M) M(0)M(1)M(2)M(3)M(4)M(5)M(6)M(7)M(8)M(9)M(10)M(11)M(12)M(13)M(14)M(15)

// ---------------- prep: transpose small weights, zero sync payload ----------------
__global__ __launch_bounds__(256) void prep_kernel(const float* __restrict__ conv_w,
                                                   const float* __restrict__ lin_w,
                                                   float* __restrict__ Wt,
                                                   float* __restrict__ linT,
                                                   float* __restrict__ sync) {
  int n = blockIdx.x * 256 + threadIdx.x;
  if (n < 16384) sync[n] = 0.f;              // 64 KB payload (tags := 0)
  if (n < 2 * FD * FD) {
    int o = n & 255, f = (n >> 8) & 255, k = n >> 16;
    Wt[n] = conv_w[o * 512 + k * 256 + f];   // Wt[k][f][o]
  } else {
    int m = n - 2 * FD * FD;
    int o = m & 255, f = m >> 8;
    linT[m] = lin_w[o * 256 + f];            // linT[f][o]
  }
}

// ---------------- char CNN + concat into x ----------------
__global__ __launch_bounds__(256) void charcnn_kernel(const float* __restrict__ wemb,
    const int* __restrict__ cidx, const float* __restrict__ cemb,
    const float* __restrict__ Wt, const float* __restrict__ conv_b,
    const float* __restrict__ linT, const float* __restrict__ lin_b,
    float* __restrict__ x) {
  __shared__ float ceT[256][20];
  __shared__ float pooled[256];
  int s = blockIdx.x, o = threadIdx.x;
  #pragma unroll
  for (int l = 0; l < 16; ++l) {
    int idx = cidx[s * 16 + l];
    ceT[o][l] = cemb[idx * 256 + o];
  }
  __syncthreads();
  float acc[15];
  float cb = conv_b[o];
  #pragma unroll
  for (int l = 0; l < 15; ++l) acc[l] = cb;
  for (int f = 0; f < 256; ++f) {
    float w0 = Wt[f * 256 + o];
    float w1 = Wt[65536 + f * 256 + o];
    float4 ca = *(const float4*)&ceT[f][0];
    float4 cv = *(const float4*)&ceT[f][4];
    float4 cc = *(const float4*)&ceT[f][8];
    float4 cd = *(const float4*)&ceT[f][12];
    float c[16] = {ca.x, ca.y, ca.z, ca.w, cv.x, cv.y, cv.z, cv.w,
                   cc.x, cc.y, cc.z, cc.w, cd.x, cd.y, cd.z, cd.w};
    #pragma unroll
    for (int l = 0; l < 15; ++l) acc[l] += c[l] * w0 + c[l + 1] * w1;
  }
  float m = 0.f;
  #pragma unroll
  for (int l = 0; l < 15; ++l) m = fmaxf(m, acc[l]);
  pooled[o] = m;
  __syncthreads();
  float a2 = lin_b[o];
  for (int f = 0; f < 256; f += 4) {
    float4 p = *(const float4*)&pooled[f];
    a2 += p.x * linT[(f + 0) * 256 + o] + p.y * linT[(f + 1) * 256 + o]
        + p.z * linT[(f + 2) * 256 + o] + p.w * linT[(f + 3) * 256 + o];
  }
  x[(size_t)s * 512 + o] = wemb[(size_t)s * 256 + o];
  x[(size_t)s * 512 + 256 + o] = a2;
}

// ---------------- input projection GEMM ----------------
__global__ __launch_bounds__(256) void xproj_kernel(const float* __restrict__ x,
    const float* __restrict__ Wih_f, const float* __restrict__ Wih_r,
    const float* __restrict__ bih_f, const float* __restrict__ bhh_f,
    const float* __restrict__ bih_r, const float* __restrict__ bhh_r,
    float* __restrict__ xproj) {
  __shared__ float As[64][33];
  __shared__ float Bs[64][33];
  int dir = blockIdx.z;
  const float* B  = dir ? Wih_r : Wih_f;
  const float* b1 = dir ? bih_r : bih_f;
  const float* b2 = dir ? bhh_r : bhh_f;
  int m0 = blockIdx.x * 64, n0 = blockIdx.y * 64;
  int tid = threadIdx.x, tx = tid & 15, ty = tid >> 4;
  float acc[4][4];
  #pragma unroll
  for (int j = 0; j < 4; ++j) {
    float bias = b1[n0 + tx * 4 + j] + b2[n0 + tx * 4 + j];
    #pragma unroll
    for (int i = 0; i < 4; ++i) acc[i][j] = bias;
  }
  int lc = tid & 31, lr0 = tid >> 5;
  for (int k0 = 0; k0 < 512; k0 += 32) {
    #pragma unroll
    for (int i = 0; i < 8; ++i) {
      As[lr0 + 8 * i][lc] = x[(size_t)(m0 + lr0 + 8 * i) * 512 + k0 + lc];
      Bs[lr0 + 8 * i][lc] = B[(size_t)(n0 + lr0 + 8 * i) * 512 + k0 + lc];
    }
    __syncthreads();
    #pragma unroll
    for (int kk = 0; kk < 32; ++kk) {
      float a0 = As[ty * 4 + 0][kk], a1 = As[ty * 4 + 1][kk];
      float a2 = As[ty * 4 + 2][kk], a3 = As[ty * 4 + 3][kk];
      float q0 = Bs[tx * 4 + 0][kk], q1 = Bs[tx * 4 + 1][kk];
      float q2 = Bs[tx * 4 + 2][kk], q3 = Bs[tx * 4 + 3][kk];
      acc[0][0] += a0 * q0; acc[0][1] += a0 * q1; acc[0][2] += a0 * q2; acc[0][3] += a0 * q3;
      acc[1][0] += a1 * q0; acc[1][1] += a1 * q1; acc[1][2] += a1 * q2; acc[1][3] += a1 * q3;
      acc[2][0] += a2 * q0; acc[2][1] += a2 * q1; acc[2][2] += a2 * q2; acc[2][3] += a2 * q3;
      acc[3][0] += a3 * q0; acc[3][1] += a3 * q1; acc[3][2] += a3 * q2; acc[3][3] += a3 * q3;
    }
    __syncthreads();
  }
  size_t base = (size_t)dir * SQ * GD;
  #pragma unroll
  for (int i = 0; i < 4; ++i) {
    float4 v = make_float4(acc[i][0], acc[i][1], acc[i][2], acc[i][3]);
    *(float4*)&xproj[base + (size_t)(m0 + ty * 4 + i) * GD + n0 + tx * 4] = v;
  }
}

// ---------------- persistent bidirectional LSTM recurrence ----------------
// 64 blocks: 0..31 fwd, 32..63 rev; block owns 16 h (64 Whh rows = 128 KB/step
// from L1/L2 -- HALF of r4's per-CU weight stream, the measured dominant term).
// Step structure identical to r4 (best proven). Protocol identical to r4:
// chunk = (tag,h0,h1,tag) as two u64 words, tag embedded in each atomically
// loaded word (no tearing, single round trip); per-lane publish words built
// from own register only; double-buffered slots; monotone tags; overwrite
// safety: every block is reader+writer, so observing all tag-t words implies
// every block consumed slot t-1.
// Layout change: each 16B chunk PADDED to its own 64B line (payload 64 KB) ->
// ~32 pollers/line (vs r4's ~64) despite 2x reader blocks.
__global__ __launch_bounds__(512, 2) void lstm_kernel(const float* __restrict__ xproj,
    const float* __restrict__ Whh_f, const float* __restrict__ Whh_r,
    u64* __restrict__ payu, float* __restrict__ out) {
  __shared__ float h4[8 * 68];    // h in 8 K-chunks of 64, pitch 68
  __shared__ float g_lds[64];
  int dir = blockIdx.x >> 5;
  int wid = blockIdx.x & 31;
  int hbase = wid * 16;
  int tid = threadIdx.x;

  int r = tid >> 3, kq = tid & 7;                 // row 0..63, K-eighth
  int Rrow = ((r >> 4) << 9) + hbase + (r & 15);  // gate*512 + hbase + j
  const float* Whh = dir ? Whh_r : Whh_f;
  const float* xp = xproj + (size_t)dir * SQ * GD;
  const f32x4* wsrc4 = (const f32x4*)(Whh + (size_t)Rrow * 512 + kq * 64);

  float cst = 0.f, hlast = 0.f;

  for (int t = 0; t < SQ; ++t) {
    int p = dir ? (SQ - 1 - t) : t;
    // weight + xval loads issued first: in flight during the poll
#define LDW(i) f32x4 w##i = wsrc4[i];
    REP16(LDW)
#undef LDW
    float xval = 0.f;
    if (kq == 0) xval = xp[(size_t)p * GD + Rrow];
    if (tid < 256) {                               // reader: chunk c = tid
      float v0, v1;
      if (t == 0) { v0 = 0.f; v1 = 0.f; }
      else {
        const u64* src = payu + (((size_t)(dir * 2 + ((t - 1) & 1)) * 256) + tid) * 8;
        unsigned tg = (unsigned)t;
        for (;;) {
          u64 lo = __hip_atomic_load(src,     __ATOMIC_RELAXED, __HIP_MEMORY_SCOPE_AGENT);
          u64 hi = __hip_atomic_load(src + 1, __ATOMIC_RELAXED, __HIP_MEMORY_SCOPE_AGENT);
          if ((unsigned)lo == tg && (unsigned)(hi >> 32) == tg) {
            v0 = __uint_as_float((unsigned)(lo >> 32));
            v1 = __uint_as_float((unsigned)hi);
            break;
          }
          __builtin_amdgcn_s_sleep(1);
        }
      }
      int ih = tid * 2;
      h4[(ih >> 6) * 68 + (ih & 63)] = v0;
      int ih1 = ih + 1;
      h4[(ih1 >> 6) * 68 + (ih1 & 63)] = v1;
    }
    __syncthreads();                               // h ready
    float a0 = 0.f, a1 = 0.f, a2 = 0.f, a3 = 0.f;
    const f32x4* hq4 = (const f32x4*)&h4[kq * 68];
#define GST(i) { f32x4 hh = hq4[i]; \
    a0 = fmaf(w##i[0], hh[0], a0); a1 = fmaf(w##i[1], hh[1], a1); \
    a2 = fmaf(w##i[2], hh[2], a2); a3 = fmaf(w##i[3], hh[3], a3); }
    REP16(GST)
#undef GST
    float acc = (a0 + a1) + (a2 + a3);
    acc += __shfl_xor(acc, 1);                     // kq reduce (8 lanes)
    acc += __shfl_xor(acc, 2);
    acc += __shfl_xor(acc, 4);
    if (kq == 0) g_lds[r] = acc + xval;
    __syncthreads();                               // g ready
    if (tid < 16) {
      float ig = g_lds[tid], fg = g_lds[16 + tid], gg = g_lds[32 + tid], og = g_lds[48 + tid];
      float c = sigf(fg) * cst + sigf(ig) * tanh_s(gg);
      float hval = sigf(og) * tanh_s(c);
      cst = c; hlast = hval;
      out[(size_t)p * 1024 + dir * 512 + hbase + tid] = hval;
      // publish: each lane stores ONE u64 built from its OWN hval.
      unsigned tg = (unsigned)(t + 1);
      u64 word = (tid & 1) ? (((u64)tg << 32) | __float_as_uint(hval))
                           : (((u64)__float_as_uint(hval) << 32) | tg);
      u64* dst = payu + (((size_t)(dir * 2 + (t & 1)) * 256) + wid * 8 + (tid >> 1)) * 8 + (tid & 1);
      __hip_atomic_store(dst, word, __ATOMIC_RELAXED, __HIP_MEMORY_SCOPE_AGENT);
    }
    // next iteration's h-ready barrier guards LDS reuse
  }
  if (tid < 16) {
    size_t OH = (size_t)SQ * 1024;
    out[OH + dir * 512 + hbase + tid] = hlast;           // hidden
    out[OH + 1024 + dir * 512 + hbase + tid] = cst;      // cell
  }
}

extern "C" void kernel_launch(void* const* d_in, const int* in_sizes, int n_in,
                              void* d_out, int out_size, void* d_ws, size_t ws_size,
                              hipStream_t stream) {
  const float* wemb   = (const float*)d_in[0];
  const int*   cidx   = (const int*)d_in[1];
  const float* cemb   = (const float*)d_in[2];
  const float* conv_w = (const float*)d_in[3];
  const float* conv_b = (const float*)d_in[4];
  const float* lin_w  = (const float*)d_in[5];
  const float* lin_b  = (const float*)d_in[6];
  const float* Wih_f  = (const float*)d_in[7];
  const float* Whh_f  = (const float*)d_in[8];
  const float* bih_f  = (const float*)d_in[9];
  const float* bhh_f  = (const float*)d_in[10];
  const float* Wih_r  = (const float*)d_in[11];
  const float* Whh_r  = (const float*)d_in[12];
  const float* bih_r  = (const float*)d_in[13];
  const float* bhh_r  = (const float*)d_in[14];
  float* out = (float*)d_out;
  float* ws = (float*)d_ws;
  float* x     = ws + WS_X;
  float* xproj = ws + WS_XPROJ;
  float* Wt    = ws + WS_WT;
  float* linT  = ws + WS_LINT;
  float* sync  = ws + WS_SYNC;

  prep_kernel<<<768, 256, 0, stream>>>(conv_w, lin_w, Wt, linT, sync);
  charcnn_kernel<<<SQ, 256, 0, stream>>>(wemb, cidx, cemb, Wt, conv_b, linT, lin_b, x);
  xproj_kernel<<<dim3(64, 32, 2), 256, 0, stream>>>(x, Wih_f, Wih_r, bih_f, bhh_f, bih_r, bhh_r, xproj);
  lstm_kernel<<<64, 512, 0, stream>>>(xproj, Whh_f, Whh_r, (u64*)sync, out);
}

// Round 12
// 8305.579 us; speedup vs baseline: 1.0158x; 1.0158x over previous
//
#include <hip/hip_runtime.h>
#include <cstdint>

#define SQ 4096
#define FD 256
#define HD 512
#define GD 2048

// workspace layout (float elements)
#define WS_X       0                         // x [4096][512]
#define WS_XPROJ   (WS_X + SQ*HD)            // xproj [2][4096][2048]
#define WS_WT      (WS_XPROJ + 2*SQ*GD)      // conv_w transposed [2][256][256]
#define WS_LINT    (WS_WT + 2*FD*FD)         // lin_w transposed [256][256]
#define WS_SYNC    (WS_LINT + FD*FD)         // payload: u64[2][2][16][16][2] = 16 KB

typedef __attribute__((ext_vector_type(4))) float f32x4;
typedef unsigned long long u64;

__device__ __forceinline__ float sigf(float x) { return 1.f / (1.f + __expf(-x)); }
// tanh(x) = 2*sigmoid(2x) - 1  (one __expf; |err| ~1e-7)
__device__ __forceinline__ float tanh_s(float x) { return fmaf(2.f, sigf(2.f * x), -1.f); }

#define REP32(M) M(0)M(1)M(2)M(3)M(4)M(5)M(6)M(7)M(8)M(9)M(10)M(11)M(12)M(13)M(14)M(15) \
                 M(16)M(17)M(18)M(19)M(20)M(21)M(22)M(23)M(24)M(25)M(26)M(27)M(28)M(29)M(30)M(31)

// ---------------- prep: transpose small weights, zero sync payload ----------------
__global__ __launch_bounds__(256) void prep_kernel(const float* __restrict__ conv_w,
                                                   const float* __restrict__ lin_w,
                                                   float* __restrict__ Wt,
                                                   float* __restrict__ linT,
                                                   float* __restrict__ sync) {
  int n = blockIdx.x * 256 + threadIdx.x;
  if (n < 4096) sync[n] = 0.f;               // 16 KB payload (tags := 0)
  if (n < 2 * FD * FD) {
    int o = n & 255, f = (n >> 8) & 255, k = n >> 16;
    Wt[n] = conv_w[o * 512 + k * 256 + f];   // Wt[k][f][o]
  } else {
    int m = n - 2 * FD * FD;
    int o = m & 255, f = m >> 8;
    linT[m] = lin_w[o * 256 + f];            // linT[f][o]
  }
}

// ---------------- char CNN + concat into x ----------------
__global__ __launch_bounds__(256) void charcnn_kernel(const float* __restrict__ wemb,
    const int* __restrict__ cidx, const float* __restrict__ cemb,
    const float* __restrict__ Wt, const float* __restrict__ conv_b,
    const float* __restrict__ linT, const float* __restrict__ lin_b,
    float* __restrict__ x) {
  __shared__ float ceT[256][20];
  __shared__ float pooled[256];
  int s = blockIdx.x, o = threadIdx.x;
  #pragma unroll
  for (int l = 0; l < 16; ++l) {
    int idx = cidx[s * 16 + l];
    ceT[o][l] = cemb[idx * 256 + o];
  }
  __syncthreads();
  float acc[15];
  float cb = conv_b[o];
  #pragma unroll
  for (int l = 0; l < 15; ++l) acc[l] = cb;
  for (int f = 0; f < 256; ++f) {
    float w0 = Wt[f * 256 + o];
    float w1 = Wt[65536 + f * 256 + o];
    float4 ca = *(const float4*)&ceT[f][0];
    float4 cv = *(const float4*)&ceT[f][4];
    float4 cc = *(const float4*)&ceT[f][8];
    float4 cd = *(const float4*)&ceT[f][12];
    float c[16] = {ca.x, ca.y, ca.z, ca.w, cv.x, cv.y, cv.z, cv.w,
                   cc.x, cc.y, cc.z, cc.w, cd.x, cd.y, cd.z, cd.w};
    #pragma unroll
    for (int l = 0; l < 15; ++l) acc[l] += c[l] * w0 + c[l + 1] * w1;
  }
  float m = 0.f;
  #pragma unroll
  for (int l = 0; l < 15; ++l) m = fmaxf(m, acc[l]);
  pooled[o] = m;
  __syncthreads();
  float a2 = lin_b[o];
  for (int f = 0; f < 256; f += 4) {
    float4 p = *(const float4*)&pooled[f];
    a2 += p.x * linT[(f + 0) * 256 + o] + p.y * linT[(f + 1) * 256 + o]
        + p.z * linT[(f + 2) * 256 + o] + p.w * linT[(f + 3) * 256 + o];
  }
  x[(size_t)s * 512 + o] = wemb[(size_t)s * 256 + o];
  x[(size_t)s * 512 + 256 + o] = a2;
}

// ---------------- input projection GEMM ----------------
__global__ __launch_bounds__(256) void xproj_kernel(const float* __restrict__ x,
    const float* __restrict__ Wih_f, const float* __restrict__ Wih_r,
    const float* __restrict__ bih_f, const float* __restrict__ bhh_f,
    const float* __restrict__ bih_r, const float* __restrict__ bhh_r,
    float* __restrict__ xproj) {
  __shared__ float As[64][33];
  __shared__ float Bs[64][33];
  int dir = blockIdx.z;
  const float* B  = dir ? Wih_r : Wih_f;
  const float* b1 = dir ? bih_r : bih_f;
  const float* b2 = dir ? bhh_r : bhh_f;
  int m0 = blockIdx.x * 64, n0 = blockIdx.y * 64;
  int tid = threadIdx.x, tx = tid & 15, ty = tid >> 4;
  float acc[4][4];
  #pragma unroll
  for (int j = 0; j < 4; ++j) {
    float bias = b1[n0 + tx * 4 + j] + b2[n0 + tx * 4 + j];
    #pragma unroll
    for (int i = 0; i < 4; ++i) acc[i][j] = bias;
  }
  int lc = tid & 31, lr0 = tid >> 5;
  for (int k0 = 0; k0 < 512; k0 += 32) {
    #pragma unroll
    for (int i = 0; i < 8; ++i) {
      As[lr0 + 8 * i][lc] = x[(size_t)(m0 + lr0 + 8 * i) * 512 + k0 + lc];
      Bs[lr0 + 8 * i][lc] = B[(size_t)(n0 + lr0 + 8 * i) * 512 + k0 + lc];
    }
    __syncthreads();
    #pragma unroll
    for (int kk = 0; kk < 32; ++kk) {
      float a0 = As[ty * 4 + 0][kk], a1 = As[ty * 4 + 1][kk];
      float a2 = As[ty * 4 + 2][kk], a3 = As[ty * 4 + 3][kk];
      float q0 = Bs[tx * 4 + 0][kk], q1 = Bs[tx * 4 + 1][kk];
      float q2 = Bs[tx * 4 + 2][kk], q3 = Bs[tx * 4 + 3][kk];
      acc[0][0] += a0 * q0; acc[0][1] += a0 * q1; acc[0][2] += a0 * q2; acc[0][3] += a0 * q3;
      acc[1][0] += a1 * q0; acc[1][1] += a1 * q1; acc[1][2] += a1 * q2; acc[1][3] += a1 * q3;
      acc[2][0] += a2 * q0; acc[2][1] += a2 * q1; acc[2][2] += a2 * q2; acc[2][3] += a2 * q3;
      acc[3][0] += a3 * q0; acc[3][1] += a3 * q1; acc[3][2] += a3 * q2; acc[3][3] += a3 * q3;
    }
    __syncthreads();
  }
  size_t base = (size_t)dir * SQ * GD;
  #pragma unroll
  for (int i = 0; i < 4; ++i) {
    float4 v = make_float4(acc[i][0], acc[i][1], acc[i][2], acc[i][3]);
    *(float4*)&xproj[base + (size_t)(m0 + ty * 4 + i) * GD + n0 + tx * 4] = v;
  }
}

// ---------------- persistent bidirectional LSTM recurrence ----------------
// Round-10 kernel (measured best steady 7.72 ms) with ONE change: the publish
// uses __hip_atomic_exchange (RMW) instead of a plain atomic store. RMWs must
// execute AT the coherence point -> dispatched immediately, not held in the
// CU write-combine queue. This A/B-tests the hypothesis that ~1.2 us of the
// 1.88 us step is writer-side store-to-visible latency (W). All protocol
// invariants unchanged (r4-proven): chunk = (tag,h0,h1,tag) as two u64 words,
// tag embedded in each atomically-accessed word, per-lane words built from
// own register only, double-buffered slots, monotone tags.
__global__ __launch_bounds__(512, 2) void lstm_kernel(const float* __restrict__ xproj,
    const float* __restrict__ Whh_f, const float* __restrict__ Whh_r,
    u64* __restrict__ payu, float* __restrict__ out) {
  __shared__ float h4[4 * 132];   // h chunked by K-quarter, pitch 132
  __shared__ float g_lds[128];
  int dir = blockIdx.x >> 4;
  int wid = blockIdx.x & 15;
  int hbase = wid * 32;
  int tid = threadIdx.x;

  int r = tid >> 2, kq = tid & 3;                 // row 0..127, K-quarter
  int Rrow = ((r >> 5) << 9) + hbase + (r & 31);  // gate*512 + hbase + hoff
  const float* Whh = dir ? Whh_r : Whh_f;
  const float* xp = xproj + (size_t)dir * SQ * GD;
  const f32x4* wsrc4 = (const f32x4*)(Whh + (size_t)Rrow * 512 + kq * 128);
#define LDW(i) f32x4 w##i = wsrc4[i];
  REP32(LDW)
#undef LDW
#define PIN(i) asm volatile("" : "+v"(w##i));
  REP32(PIN)
#undef PIN

  int ib = tid >> 4, ic = tid & 15;               // reader: writer-block, chunk
  float cst = 0.f, hlast = 0.f;

  for (int t = 0; t < SQ; ++t) {
    int p = dir ? (SQ - 1 - t) : t;
    float xval = 0.f;
    if (kq == 0) xval = xp[(size_t)p * GD + Rrow];   // prefetch before poll
    if (tid < 256) {
      float v0, v1;
      if (t == 0) { v0 = 0.f; v1 = 0.f; }
      else {
        const u64* src = payu + ((((size_t)dir * 2 + ((t - 1) & 1)) * 16 + ib) * 16 + ic) * 2;
        unsigned tg = (unsigned)t;
        for (;;) {
          u64 lo = __hip_atomic_load(src,     __ATOMIC_RELAXED, __HIP_MEMORY_SCOPE_AGENT);
          u64 hi = __hip_atomic_load(src + 1, __ATOMIC_RELAXED, __HIP_MEMORY_SCOPE_AGENT);
          if ((unsigned)lo == tg && (unsigned)(hi >> 32) == tg) {
            v0 = __uint_as_float((unsigned)(lo >> 32));
            v1 = __uint_as_float((unsigned)hi);
            break;
          }
          __builtin_amdgcn_s_sleep(1);
        }
      }
      int ih = ib * 32 + ic * 2;
      h4[(ih >> 7) * 132 + (ih & 127)] = v0;
      int ih1 = ih + 1;
      h4[(ih1 >> 7) * 132 + (ih1 & 127)] = v1;
    }
    __syncthreads();                               // h ready
    float a0 = 0.f, a1 = 0.f, a2 = 0.f, a3 = 0.f;
    const f32x4* hq4 = (const f32x4*)&h4[kq * 132];
#define GST(i) { f32x4 hh = hq4[i]; \
    a0 = fmaf(w##i[0], hh[0], a0); a1 = fmaf(w##i[1], hh[1], a1); \
    a2 = fmaf(w##i[2], hh[2], a2); a3 = fmaf(w##i[3], hh[3], a3); }
    REP32(GST)
#undef GST
    float acc = (a0 + a1) + (a2 + a3);
    acc += __shfl_xor(acc, 1);
    acc += __shfl_xor(acc, 2);
    if (kq == 0) g_lds[r] = acc + xval;
    __syncthreads();                               // g ready
    if (tid < 32) {
      float ig = g_lds[tid], fg = g_lds[32 + tid], gg = g_lds[64 + tid], og = g_lds[96 + tid];
      float c = sigf(fg) * cst + sigf(ig) * tanh_s(gg);
      float hval = sigf(og) * tanh_s(c);
      cst = c; hlast = hval;
      out[(size_t)p * 1024 + dir * 512 + hbase + tid] = hval;
      // publish via atomic EXCHANGE (RMW executes at the coherence point ->
      // immediate visibility; old value consumed to keep the returning form)
      unsigned tg = (unsigned)(t + 1);
      u64 word = (tid & 1) ? (((u64)tg << 32) | __float_as_uint(hval))
                           : (((u64)__float_as_uint(hval) << 32) | tg);
      u64* dst = payu + ((((size_t)dir * 2 + (t & 1)) * 16 + wid) * 16 + (tid >> 1)) * 2 + (tid & 1);
      u64 old = __hip_atomic_exchange(dst, word, __ATOMIC_RELAXED, __HIP_MEMORY_SCOPE_AGENT);
      asm volatile("" :: "v"(old));
    }
    // next iteration's h-ready barrier guards LDS reuse
  }
  if (tid < 32) {
    size_t OH = (size_t)SQ * 1024;
    out[OH + dir * 512 + hbase + tid] = hlast;           // hidden
    out[OH + 1024 + dir * 512 + hbase + tid] = cst;      // cell
  }
}

extern "C" void kernel_launch(void* const* d_in, const int* in_sizes, int n_in,
                              void* d_out, int out_size, void* d_ws, size_t ws_size,
                              hipStream_t stream) {
  const float* wemb   = (const float*)d_in[0];
  const int*   cidx   = (const int*)d_in[1];
  const float* cemb   = (const float*)d_in[2];
  const float* conv_w = (const float*)d_in[3];
  const float* conv_b = (const float*)d_in[4];
  const float* lin_w  = (const float*)d_in[5];
  const float* lin_b  = (const float*)d_in[6];
  const float* Wih_f  = (const float*)d_in[7];
  const float* Whh_f  = (const float*)d_in[8];
  const float* bih_f  = (const float*)d_in[9];
  const float* bhh_f  = (const float*)d_in[10];
  const float* Wih_r  = (const float*)d_in[11];
  const float* Whh_r  = (const float*)d_in[12];
  const float* bih_r  = (const float*)d_in[13];
  const float* bhh_r  = (const float*)d_in[14];
  float* out = (float*)d_out;
  float* ws = (float*)d_ws;
  float* x     = ws + WS_X;
  float* xproj = ws + WS_XPROJ;
  float* Wt    = ws + WS_WT;
  float* linT  = ws + WS_LINT;
  float* sync  = ws + WS_SYNC;

  prep_kernel<<<768, 256, 0, stream>>>(conv_w, lin_w, Wt, linT, sync);
  charcnn_kernel<<<SQ, 256, 0, stream>>>(wemb, cidx, cemb, Wt, conv_b, linT, lin_b, x);
  xproj_kernel<<<dim3(64, 32, 2), 256, 0, stream>>>(x, Wih_f, Wih_r, bih_f, bhh_f, bih_r, bhh_r, xproj);
  lstm_kernel<<<32, 512, 0, stream>>>(xproj, Whh_f, Whh_r, (u64*)sync, out);
}

// Round 13
// 7639.037 us; speedup vs baseline: 1.1044x; 1.0873x over previous
//
#include <hip/hip_runtime.h>
#include <cstdint>

#define SQ 4096
#define FD 256
#define HD 512
#define GD 2048

// workspace layout (float elements)
#define WS_X       0                         // x [4096][512]
#define WS_XPROJ   (WS_X + SQ*HD)            // xproj [2][4096][2048]
#define WS_WT      (WS_XPROJ + 2*SQ*GD)      // conv_w transposed [2][256][256]
#define WS_LINT    (WS_WT + 2*FD*FD)         // lin_w transposed [256][256]
#define WS_SYNC    (WS_LINT + FD*FD)         // payload: u64[2][2][256][2] = 16 KB

typedef __attribute__((ext_vector_type(4))) float f32x4;
typedef unsigned long long u64;

__device__ __forceinline__ float sigf(float x) { return 1.f / (1.f + __expf(-x)); }
// tanh(x) = 2*sigmoid(2x) - 1  (one __expf; |err| ~1e-7)
__device__ __forceinline__ float tanh_s(float x) { return fmaf(2.f, sigf(2.f * x), -1.f); }

#define REP8(M) M(0)M(1)M(2)M(3)M(4)M(5)M(6)M(7)

// ---------------- prep: transpose small weights, zero sync payload ----------------
__global__ __launch_bounds__(256) void prep_kernel(const float* __restrict__ conv_w,
                                                   const float* __restrict__ lin_w,
                                                   float* __restrict__ Wt,
                                                   float* __restrict__ linT,
                                                   float* __restrict__ sync) {
  int n = blockIdx.x * 256 + threadIdx.x;
  if (n < 4096) sync[n] = 0.f;               // 16 KB payload (tags := 0)
  if (n < 2 * FD * FD) {
    int o = n & 255, f = (n >> 8) & 255, k = n >> 16;
    Wt[n] = conv_w[o * 512 + k * 256 + f];   // Wt[k][f][o]
  } else {
    int m = n - 2 * FD * FD;
    int o = m & 255, f = m >> 8;
    linT[m] = lin_w[o * 256 + f];            // linT[f][o]
  }
}

// ---------------- char CNN + concat into x ----------------
__global__ __launch_bounds__(256) void charcnn_kernel(const float* __restrict__ wemb,
    const int* __restrict__ cidx, const float* __restrict__ cemb,
    const float* __restrict__ Wt, const float* __restrict__ conv_b,
    const float* __restrict__ linT, const float* __restrict__ lin_b,
    float* __restrict__ x) {
  __shared__ float ceT[256][20];
  __shared__ float pooled[256];
  int s = blockIdx.x, o = threadIdx.x;
  #pragma unroll
  for (int l = 0; l < 16; ++l) {
    int idx = cidx[s * 16 + l];
    ceT[o][l] = cemb[idx * 256 + o];
  }
  __syncthreads();
  float acc[15];
  float cb = conv_b[o];
  #pragma unroll
  for (int l = 0; l < 15; ++l) acc[l] = cb;
  for (int f = 0; f < 256; ++f) {
    float w0 = Wt[f * 256 + o];
    float w1 = Wt[65536 + f * 256 + o];
    float4 ca = *(const float4*)&ceT[f][0];
    float4 cv = *(const float4*)&ceT[f][4];
    float4 cc = *(const float4*)&ceT[f][8];
    float4 cd = *(const float4*)&ceT[f][12];
    float c[16] = {ca.x, ca.y, ca.z, ca.w, cv.x, cv.y, cv.z, cv.w,
                   cc.x, cc.y, cc.z, cc.w, cd.x, cd.y, cd.z, cd.w};
    #pragma unroll
    for (int l = 0; l < 15; ++l) acc[l] += c[l] * w0 + c[l + 1] * w1;
  }
  float m = 0.f;
  #pragma unroll
  for (int l = 0; l < 15; ++l) m = fmaxf(m, acc[l]);
  pooled[o] = m;
  __syncthreads();
  float a2 = lin_b[o];
  for (int f = 0; f < 256; f += 4) {
    float4 p = *(const float4*)&pooled[f];
    a2 += p.x * linT[(f + 0) * 256 + o] + p.y * linT[(f + 1) * 256 + o]
        + p.z * linT[(f + 2) * 256 + o] + p.w * linT[(f + 3) * 256 + o];
  }
  x[(size_t)s * 512 + o] = wemb[(size_t)s * 256 + o];
  x[(size_t)s * 512 + 256 + o] = a2;
}

// ---------------- input projection GEMM ----------------
__global__ __launch_bounds__(256) void xproj_kernel(const float* __restrict__ x,
    const float* __restrict__ Wih_f, const float* __restrict__ Wih_r,
    const float* __restrict__ bih_f, const float* __restrict__ bhh_f,
    const float* __restrict__ bih_r, const float* __restrict__ bhh_r,
    float* __restrict__ xproj) {
  __shared__ float As[64][33];
  __shared__ float Bs[64][33];
  int dir = blockIdx.z;
  const float* B  = dir ? Wih_r : Wih_f;
  const float* b1 = dir ? bih_r : bih_f;
  const float* b2 = dir ? bhh_r : bhh_f;
  int m0 = blockIdx.x * 64, n0 = blockIdx.y * 64;
  int tid = threadIdx.x, tx = tid & 15, ty = tid >> 4;
  float acc[4][4];
  #pragma unroll
  for (int j = 0; j < 4; ++j) {
    float bias = b1[n0 + tx * 4 + j] + b2[n0 + tx * 4 + j];
    #pragma unroll
    for (int i = 0; i < 4; ++i) acc[i][j] = bias;
  }
  int lc = tid & 31, lr0 = tid >> 5;
  for (int k0 = 0; k0 < 512; k0 += 32) {
    #pragma unroll
    for (int i = 0; i < 8; ++i) {
      As[lr0 + 8 * i][lc] = x[(size_t)(m0 + lr0 + 8 * i) * 512 + k0 + lc];
      Bs[lr0 + 8 * i][lc] = B[(size_t)(n0 + lr0 + 8 * i) * 512 + k0 + lc];
    }
    __syncthreads();
    #pragma unroll
    for (int kk = 0; kk < 32; ++kk) {
      float a0 = As[ty * 4 + 0][kk], a1 = As[ty * 4 + 1][kk];
      float a2 = As[ty * 4 + 2][kk], a3 = As[ty * 4 + 3][kk];
      float q0 = Bs[tx * 4 + 0][kk], q1 = Bs[tx * 4 + 1][kk];
      float q2 = Bs[tx * 4 + 2][kk], q3 = Bs[tx * 4 + 3][kk];
      acc[0][0] += a0 * q0; acc[0][1] += a0 * q1; acc[0][2] += a0 * q2; acc[0][3] += a0 * q3;
      acc[1][0] += a1 * q0; acc[1][1] += a1 * q1; acc[1][2] += a1 * q2; acc[1][3] += a1 * q3;
      acc[2][0] += a2 * q0; acc[2][1] += a2 * q1; acc[2][2] += a2 * q2; acc[2][3] += a2 * q3;
      acc[3][0] += a3 * q0; acc[3][1] += a3 * q1; acc[3][2] += a3 * q2; acc[3][3] += a3 * q3;
    }
    __syncthreads();
  }
  size_t base = (size_t)dir * SQ * GD;
  #pragma unroll
  for (int i = 0; i < 4; ++i) {
    float4 v = make_float4(acc[i][0], acc[i][1], acc[i][2], acc[i][3]);
    *(float4*)&xproj[base + (size_t)(m0 + ty * 4 + i) * GD + n0 + tx * 4] = v;
  }
}

// ---------------- persistent bidirectional LSTM recurrence ----------------
// 64 blocks x 1024 threads: 0..31 fwd, 32..63 rev; block owns 16 h (64 rows).
// Thread = (row r 0..63, kq 0..15): 32 weights = 8 f32x4 = 32 VGPR -- small
// enough that the pinned loads can stay register-resident (r10's pin failed
// at 128 VGPRs of weights; r4..r12 counters proved the allocator otherwise
// re-materializes weight loads AFTER the h barrier = serialized L2-latency
// batches on the critical path, the last unexplained ~1 us of the step).
// Protocol identical to r12 (proven): 16B chunk = (tag,h0,h1,tag) as two u64
// words, tag embedded in each atomically-accessed word (no tearing, single
// round trip); per-lane publish words built from own register only; RMW
// exchange publish; double-buffered slots; monotone tags. Overwrite safety:
// seeing all tag-t words implies every block finished step t-1's read of
// slot t&1 ((t-2)&1 == t&1), so publishing tag t+1 there is safe.
__global__ __launch_bounds__(1024, 4) void lstm_kernel(const float* __restrict__ xproj,
    const float* __restrict__ Whh_f, const float* __restrict__ Whh_r,
    u64* __restrict__ payu, float* __restrict__ out) {
  __shared__ float h4[16 * 36];   // h in 16 kq-slices of 32, pitch 36
  __shared__ float g_lds[64];
  int dir = blockIdx.x >> 5;
  int wid = blockIdx.x & 31;
  int hbase = wid * 16;
  int tid = threadIdx.x;

  int r = tid >> 4, kq = tid & 15;                // row 0..63, K-sixteenth
  int Rrow = ((r >> 4) << 9) + hbase + (r & 15);  // gate*512 + hbase + j
  const float* Whh = dir ? Whh_r : Whh_f;
  const float* xp = xproj + (size_t)dir * SQ * GD;
  const f32x4* wsrc4 = (const f32x4*)(Whh + (size_t)Rrow * 512 + kq * 32);
#define LDW(i) f32x4 w##i = wsrc4[i];
  REP8(LDW)
#undef LDW
  // pin: forbids sinking/remat of the loads into the loop (32 VGPR of weights)
#define PIN(i) asm volatile("" : "+v"(w##i));
  REP8(PIN)
#undef PIN

  float cst = 0.f, hlast = 0.f;

  for (int t = 0; t < SQ; ++t) {
    int p = dir ? (SQ - 1 - t) : t;
    float xval = 0.f;
    if (kq == 0) xval = xp[(size_t)p * GD + Rrow];   // prefetch before poll
    if (tid < 256) {                                 // reader: chunk c = tid
      float v0, v1;
      if (t == 0) { v0 = 0.f; v1 = 0.f; }
      else {
        const u64* src = payu + (((size_t)(dir * 2 + ((t - 1) & 1)) * 256) + tid) * 2;
        unsigned tg = (unsigned)t;
        for (;;) {
          u64 lo = __hip_atomic_load(src,     __ATOMIC_RELAXED, __HIP_MEMORY_SCOPE_AGENT);
          u64 hi = __hip_atomic_load(src + 1, __ATOMIC_RELAXED, __HIP_MEMORY_SCOPE_AGENT);
          if ((unsigned)lo == tg && (unsigned)(hi >> 32) == tg) {
            v0 = __uint_as_float((unsigned)(lo >> 32));
            v1 = __uint_as_float((unsigned)hi);
            break;
          }
          __builtin_amdgcn_s_sleep(1);
        }
      }
      int ih = tid * 2;                              // h index 0..511
      int sl = ih >> 5, off = ih & 31;
      h4[sl * 36 + off] = v0;
      h4[sl * 36 + off + 1] = v1;
    }
    __syncthreads();                                 // h ready
    float a0 = 0.f, a1 = 0.f, a2 = 0.f, a3 = 0.f;
    const f32x4* hq4 = (const f32x4*)&h4[kq * 36];
#define GST(i) { f32x4 hh = hq4[i]; \
    a0 = fmaf(w##i[0], hh[0], a0); a1 = fmaf(w##i[1], hh[1], a1); \
    a2 = fmaf(w##i[2], hh[2], a2); a3 = fmaf(w##i[3], hh[3], a3); }
    REP8(GST)
#undef GST
    float acc = (a0 + a1) + (a2 + a3);
    acc += __shfl_xor(acc, 1);                       // kq reduce (16 lanes)
    acc += __shfl_xor(acc, 2);
    acc += __shfl_xor(acc, 4);
    acc += __shfl_xor(acc, 8);
    if (kq == 0) g_lds[r] = acc + xval;
    __syncthreads();                                 // g ready
    if (tid < 16) {
      float ig = g_lds[tid], fg = g_lds[16 + tid], gg = g_lds[32 + tid], og = g_lds[48 + tid];
      float c = sigf(fg) * cst + sigf(ig) * tanh_s(gg);
      float hval = sigf(og) * tanh_s(c);
      cst = c; hlast = hval;
      out[(size_t)p * 1024 + dir * 512 + hbase + tid] = hval;
      // publish: each lane stores ONE u64 built from its OWN hval (RMW).
      unsigned tg = (unsigned)(t + 1);
      u64 word = (tid & 1) ? (((u64)tg << 32) | __float_as_uint(hval))
                           : (((u64)__float_as_uint(hval) << 32) | tg);
      u64* dst = payu + (((size_t)(dir * 2 + (t & 1)) * 256) + wid * 8 + (tid >> 1)) * 2 + (tid & 1);
      u64 old = __hip_atomic_exchange(dst, word, __ATOMIC_RELAXED, __HIP_MEMORY_SCOPE_AGENT);
      asm volatile("" :: "v"(old));
    }
    // next iteration's h-ready barrier guards LDS reuse
  }
  if (tid < 16) {
    size_t OH = (size_t)SQ * 1024;
    out[OH + dir * 512 + hbase + tid] = hlast;           // hidden
    out[OH + 1024 + dir * 512 + hbase + tid] = cst;      // cell
  }
}

extern "C" void kernel_launch(void* const* d_in, const int* in_sizes, int n_in,
                              void* d_out, int out_size, void* d_ws, size_t ws_size,
                              hipStream_t stream) {
  const float* wemb   = (const float*)d_in[0];
  const int*   cidx   = (const int*)d_in[1];
  const float* cemb   = (const float*)d_in[2];
  const float* conv_w = (const float*)d_in[3];
  const float* conv_b = (const float*)d_in[4];
  const float* lin_w  = (const float*)d_in[5];
  const float* lin_b  = (const float*)d_in[6];
  const float* Wih_f  = (const float*)d_in[7];
  const float* Whh_f  = (const float*)d_in[8];
  const float* bih_f  = (const float*)d_in[9];
  const float* bhh_f  = (const float*)d_in[10];
  const float* Wih_r  = (const float*)d_in[11];
  const float* Whh_r  = (const float*)d_in[12];
  const float* bih_r  = (const float*)d_in[13];
  const float* bhh_r  = (const float*)d_in[14];
  float* out = (float*)d_out;
  float* ws = (float*)d_ws;
  float* x     = ws + WS_X;
  float* xproj = ws + WS_XPROJ;
  float* Wt    = ws + WS_WT;
  float* linT  = ws + WS_LINT;
  float* sync  = ws + WS_SYNC;

  prep_kernel<<<768, 256, 0, stream>>>(conv_w, lin_w, Wt, linT, sync);
  charcnn_kernel<<<SQ, 256, 0, stream>>>(wemb, cidx, cemb, Wt, conv_b, linT, lin_b, x);
  xproj_kernel<<<dim3(64, 32, 2), 256, 0, stream>>>(x, Wih_f, Wih_r, bih_f, bhh_f, bih_r, bhh_r, xproj);
  lstm_kernel<<<64, 1024, 0, stream>>>(xproj, Whh_f, Whh_r, (u64*)sync, out);
}

// Round 14
// 7499.178 us; speedup vs baseline: 1.1250x; 1.0186x over previous
//
#include <hip/hip_runtime.h>
#include <cstdint>

#define SQ 4096
#define FD 256
#define HD 512
#define GD 2048

// workspace layout (float elements)
#define WS_X       0                         // x [4096][512]
#define WS_XPROJ   (WS_X + SQ*HD)            // xproj [2][4096][2048]
#define WS_WT      (WS_XPROJ + 2*SQ*GD)      // conv_w transposed [2][256][256]
#define WS_LINT    (WS_WT + 2*FD*FD)         // lin_w transposed [256][256]
#define WS_SYNC    (WS_LINT + FD*FD)         // payload: u64[2 dir][2 slot][512] = 16 KB

typedef __attribute__((ext_vector_type(4))) float f32x4;
typedef unsigned long long u64;

__device__ __forceinline__ float sigf(float x) { return 1.f / (1.f + __expf(-x)); }
// tanh(x) = 2*sigmoid(2x) - 1  (one __expf; |err| ~1e-7)
__device__ __forceinline__ float tanh_s(float x) { return fmaf(2.f, sigf(2.f * x), -1.f); }

#define REP8(M) M(0)M(1)M(2)M(3)M(4)M(5)M(6)M(7)

// ---------------- prep: transpose small weights, zero sync payload ----------------
__global__ __launch_bounds__(256) void prep_kernel(const float* __restrict__ conv_w,
                                                   const float* __restrict__ lin_w,
                                                   float* __restrict__ Wt,
                                                   float* __restrict__ linT,
                                                   float* __restrict__ sync) {
  int n = blockIdx.x * 256 + threadIdx.x;
  if (n < 4096) sync[n] = 0.f;               // 16 KB payload (tags := 0)
  if (n < 2 * FD * FD) {
    int o = n & 255, f = (n >> 8) & 255, k = n >> 16;
    Wt[n] = conv_w[o * 512 + k * 256 + f];   // Wt[k][f][o]
  } else {
    int m = n - 2 * FD * FD;
    int o = m & 255, f = m >> 8;
    linT[m] = lin_w[o * 256 + f];            // linT[f][o]
  }
}

// ---------------- char CNN + concat into x ----------------
__global__ __launch_bounds__(256) void charcnn_kernel(const float* __restrict__ wemb,
    const int* __restrict__ cidx, const float* __restrict__ cemb,
    const float* __restrict__ Wt, const float* __restrict__ conv_b,
    const float* __restrict__ linT, const float* __restrict__ lin_b,
    float* __restrict__ x) {
  __shared__ float ceT[256][20];
  __shared__ float pooled[256];
  int s = blockIdx.x, o = threadIdx.x;
  #pragma unroll
  for (int l = 0; l < 16; ++l) {
    int idx = cidx[s * 16 + l];
    ceT[o][l] = cemb[idx * 256 + o];
  }
  __syncthreads();
  float acc[15];
  float cb = conv_b[o];
  #pragma unroll
  for (int l = 0; l < 15; ++l) acc[l] = cb;
  for (int f = 0; f < 256; ++f) {
    float w0 = Wt[f * 256 + o];
    float w1 = Wt[65536 + f * 256 + o];
    float4 ca = *(const float4*)&ceT[f][0];
    float4 cv = *(const float4*)&ceT[f][4];
    float4 cc = *(const float4*)&ceT[f][8];
    float4 cd = *(const float4*)&ceT[f][12];
    float c[16] = {ca.x, ca.y, ca.z, ca.w, cv.x, cv.y, cv.z, cv.w,
                   cc.x, cc.y, cc.z, cc.w, cd.x, cd.y, cd.z, cd.w};
    #pragma unroll
    for (int l = 0; l < 15; ++l) acc[l] += c[l] * w0 + c[l + 1] * w1;
  }
  float m = 0.f;
  #pragma unroll
  for (int l = 0; l < 15; ++l) m = fmaxf(m, acc[l]);
  pooled[o] = m;
  __syncthreads();
  float a2 = lin_b[o];
  for (int f = 0; f < 256; f += 4) {
    float4 p = *(const float4*)&pooled[f];
    a2 += p.x * linT[(f + 0) * 256 + o] + p.y * linT[(f + 1) * 256 + o]
        + p.z * linT[(f + 2) * 256 + o] + p.w * linT[(f + 3) * 256 + o];
  }
  x[(size_t)s * 512 + o] = wemb[(size_t)s * 256 + o];
  x[(size_t)s * 512 + 256 + o] = a2;
}

// ---------------- input projection GEMM ----------------
__global__ __launch_bounds__(256) void xproj_kernel(const float* __restrict__ x,
    const float* __restrict__ Wih_f, const float* __restrict__ Wih_r,
    const float* __restrict__ bih_f, const float* __restrict__ bhh_f,
    const float* __restrict__ bih_r, const float* __restrict__ bhh_r,
    float* __restrict__ xproj) {
  __shared__ float As[64][33];
  __shared__ float Bs[64][33];
  int dir = blockIdx.z;
  const float* B  = dir ? Wih_r : Wih_f;
  const float* b1 = dir ? bih_r : bih_f;
  const float* b2 = dir ? bhh_r : bhh_f;
  int m0 = blockIdx.x * 64, n0 = blockIdx.y * 64;
  int tid = threadIdx.x, tx = tid & 15, ty = tid >> 4;
  float acc[4][4];
  #pragma unroll
  for (int j = 0; j < 4; ++j) {
    float bias = b1[n0 + tx * 4 + j] + b2[n0 + tx * 4 + j];
    #pragma unroll
    for (int i = 0; i < 4; ++i) acc[i][j] = bias;
  }
  int lc = tid & 31, lr0 = tid >> 5;
  for (int k0 = 0; k0 < 512; k0 += 32) {
    #pragma unroll
    for (int i = 0; i < 8; ++i) {
      As[lr0 + 8 * i][lc] = x[(size_t)(m0 + lr0 + 8 * i) * 512 + k0 + lc];
      Bs[lr0 + 8 * i][lc] = B[(size_t)(n0 + lr0 + 8 * i) * 512 + k0 + lc];
    }
    __syncthreads();
    #pragma unroll
    for (int kk = 0; kk < 32; ++kk) {
      float a0 = As[ty * 4 + 0][kk], a1 = As[ty * 4 + 1][kk];
      float a2 = As[ty * 4 + 2][kk], a3 = As[ty * 4 + 3][kk];
      float q0 = Bs[tx * 4 + 0][kk], q1 = Bs[tx * 4 + 1][kk];
      float q2 = Bs[tx * 4 + 2][kk], q3 = Bs[tx * 4 + 3][kk];
      acc[0][0] += a0 * q0; acc[0][1] += a0 * q1; acc[0][2] += a0 * q2; acc[0][3] += a0 * q3;
      acc[1][0] += a1 * q0; acc[1][1] += a1 * q1; acc[1][2] += a1 * q2; acc[1][3] += a1 * q3;
      acc[2][0] += a2 * q0; acc[2][1] += a2 * q1; acc[2][2] += a2 * q2; acc[2][3] += a2 * q3;
      acc[3][0] += a3 * q0; acc[3][1] += a3 * q1; acc[3][2] += a3 * q2; acc[3][3] += a3 * q3;
    }
    __syncthreads();
  }
  size_t base = (size_t)dir * SQ * GD;
  #pragma unroll
  for (int i = 0; i < 4; ++i) {
    float4 v = make_float4(acc[i][0], acc[i][1], acc[i][2], acc[i][3]);
    *(float4*)&xproj[base + (size_t)(m0 + ty * 4 + i) * GD + n0 + tx * 4] = v;
  }
}

// ---------------- persistent bidirectional LSTM recurrence ----------------
// 64 blocks x 1024 threads: 0..31 fwd, 32..63 rev; block owns 16 h (64 rows).
// Wave w (0..15) owns h-index j=w: lane = gate*16 + kq; 32 weights/thread.
// Payload: ONE u64 per h per slot = (tag<<32)|h_bits (r7-proven, no tearing;
// single poll load per round). Double slot; monotone tags; RMW publish (r12).
// Step = stage(LDS, dbuf) -> ONE barrier -> in-wave GEMV + shfl reduce +
// parallel activations at kq==0 lanes + lane-0 gather/c,h -> publish.
// No g_lds, no second barrier (cut from r13's critical path).
// LDS dbuf safety (1 barrier): stage at t+2 reuses buf of t; fast wave passed
// barrier(t+1) which required all waves done staging t+1, which follows their
// step-t GEMV reads -- so no wave still reads buf when overwritten.
// Global overwrite safety (r4 proof, wave-sliced form): each wave's 16-lane
// kq group covers ALL of K, so ANY wave publishing tag t+1 implies its block
// passed barrier t+1, i.e. its stagers saw tag t on ALL 512 words, i.e. every
// block published t and is done reading tag t-1 from the slot being reused.
__global__ __launch_bounds__(1024, 4) void lstm_kernel(const float* __restrict__ xproj,
    const float* __restrict__ Whh_f, const float* __restrict__ Whh_r,
    u64* __restrict__ payu, float* __restrict__ out) {
  __shared__ float hl[2][16 * 36];   // double-buffered h: 16 kq-slices of 32, pitch 36
  int dir = blockIdx.x >> 5;
  int wid = blockIdx.x & 31;
  int hbase = wid * 16;
  int tid = threadIdx.x;
  int w = tid >> 6, lane = tid & 63;
  int gate = lane >> 4, kq = lane & 15;
  int Rrow = (gate << 9) + hbase + w;              // gate*512 + hbase + j(=w)
  const float* Whh = dir ? Whh_r : Whh_f;
  const float* xp = xproj + (size_t)dir * SQ * GD;
  const f32x4* wsrc4 = (const f32x4*)(Whh + (size_t)Rrow * 512 + kq * 32);
#define LDW(i) f32x4 w##i = wsrc4[i];
  REP8(LDW)
#undef LDW
#define PIN(i) asm volatile("" : "+v"(w##i));
  REP8(PIN)
#undef PIN
  u64* mypay = payu + (size_t)dir * 1024;          // [slot][512]

  const bool lz = (lane == 0);                     // gate lane of wave w
  float cst = 0.f, hlast = 0.f;

  for (int t = 0; t < SQ; ++t) {
    int p = dir ? (SQ - 1 - t) : t;
    float xval = 0.f;
    if (kq == 0) xval = xp[(size_t)p * GD + Rrow]; // issued early, in flight
    int buf = (t + 1) & 1;                         // stage h(t-1) into this buf
    if (tid < 512) {                               // stager: one u64 word each
      float hv;
      if (t == 0) hv = 0.f;
      else {
        const u64* src = mypay + ((t - 1) & 1) * 512 + tid;
        unsigned tg = (unsigned)t;
        u64 v;
        do { v = __hip_atomic_load(src, __ATOMIC_RELAXED, __HIP_MEMORY_SCOPE_AGENT); }
        while ((unsigned)(v >> 32) != tg);
        hv = __uint_as_float((unsigned)v);
      }
      hl[buf][(tid >> 5) * 36 + (tid & 31)] = hv;
    }
    __syncthreads();                               // h ready (sole barrier)
    float a0 = 0.f, a1 = 0.f, a2 = 0.f, a3 = 0.f;
    const f32x4* hq4 = (const f32x4*)&hl[buf][kq * 36];
#define GST(i) { f32x4 hh = hq4[i]; \
    a0 = fmaf(w##i[0], hh[0], a0); a1 = fmaf(w##i[1], hh[1], a1); \
    a2 = fmaf(w##i[2], hh[2], a2); a3 = fmaf(w##i[3], hh[3], a3); }
    REP8(GST)
#undef GST
    float acc = (a0 + a1) + (a2 + a3);
    acc += __shfl_xor(acc, 1);                     // kq reduce (16 lanes)
    acc += __shfl_xor(acc, 2);
    acc += __shfl_xor(acc, 4);
    acc += __shfl_xor(acc, 8);
    float gx = acc + xval;                         // valid at kq==0 lanes
    // parallel activation at the 4 kq==0 lanes (gate 2 = tanh, else sigmoid)
    float act = (gate == 2) ? tanh_s(gx) : sigf(gx);
    float aI = __shfl(act, 0);                     // in-wave gather (full wave)
    float aF = __shfl(act, 16);
    float aG = __shfl(act, 32);
    float aO = __shfl(act, 48);
    if (lz) {
      float c = aF * cst + aI * aG;
      float hval = aO * tanh_s(c);
      cst = c; hlast = hval;
      // publish FIRST (RMW executes at coherence point), then output store
      u64 word = ((u64)(unsigned)(t + 1) << 32) | __float_as_uint(hval);
      u64 old = __hip_atomic_exchange(mypay + (t & 1) * 512 + hbase + w, word,
                                      __ATOMIC_RELAXED, __HIP_MEMORY_SCOPE_AGENT);
      asm volatile("" :: "v"(old));
      out[(size_t)p * 1024 + dir * 512 + hbase + w] = hval;
    }
  }
  if (lz) {
    size_t OH = (size_t)SQ * 1024;
    out[OH + dir * 512 + hbase + w] = hlast;       // hidden
    out[OH + 1024 + dir * 512 + hbase + w] = cst;  // cell
  }
}

extern "C" void kernel_launch(void* const* d_in, const int* in_sizes, int n_in,
                              void* d_out, int out_size, void* d_ws, size_t ws_size,
                              hipStream_t stream) {
  const float* wemb   = (const float*)d_in[0];
  const int*   cidx   = (const int*)d_in[1];
  const float* cemb   = (const float*)d_in[2];
  const float* conv_w = (const float*)d_in[3];
  const float* conv_b = (const float*)d_in[4];
  const float* lin_w  = (const float*)d_in[5];
  const float* lin_b  = (const float*)d_in[6];
  const float* Wih_f  = (const float*)d_in[7];
  const float* Whh_f  = (const float*)d_in[8];
  const float* bih_f  = (const float*)d_in[9];
  const float* bhh_f  = (const float*)d_in[10];
  const float* Wih_r  = (const float*)d_in[11];
  const float* Whh_r  = (const float*)d_in[12];
  const float* bih_r  = (const float*)d_in[13];
  const float* bhh_r  = (const float*)d_in[14];
  float* out = (float*)d_out;
  float* ws = (float*)d_ws;
  float* x     = ws + WS_X;
  float* xproj = ws + WS_XPROJ;
  float* Wt    = ws + WS_WT;
  float* linT  = ws + WS_LINT;
  float* sync  = ws + WS_SYNC;

  prep_kernel<<<768, 256, 0, stream>>>(conv_w, lin_w, Wt, linT, sync);
  charcnn_kernel<<<SQ, 256, 0, stream>>>(wemb, cidx, cemb, Wt, conv_b, linT, lin_b, x);
  xproj_kernel<<<dim3(64, 32, 2), 256, 0, stream>>>(x, Wih_f, Wih_r, bih_f, bhh_f, bih_r, bhh_r, xproj);
  lstm_kernel<<<64, 1024, 0, stream>>>(xproj, Whh_f, Whh_r, (u64*)sync, out);
}